// Round 4
// baseline (217.411 us; speedup 1.0000x reference)
//
#include <hip/hip_runtime.h>

// NURBS surface eval, two-stage separable form.
//   Per block: one batch b x TU=4 U-rows. 256 threads, 8192 blocks.
//   Stage 1: rows[u][n] = sum_l Nu[U,l]*ctrl[b,iu[U,l],n]  (1 point/thread)
//   Stage 2: thread t owns V-pair (2t,2t+1); consecutive-base trick
//     (iv[2t+1].x - iv[2t].x in {0,1}; knot intervals span ~8.5 samples):
//     5 consecutive float4 gathers cover both points, point B uses a 5-wide
//     weight vector selected once. ALL 4 u-rows staged to LDS (24 KB).
//   Store phase: after ONE barrier, read staging back linearly and store
//     lane-contiguous dwordx4 -> every store instruction fully covers its
//     64-B lines (fixes the 1/3-line-coverage ~2.2 TB/s effective drain of
//     direct 12 B/point stores). No barrier follows any global store, so no
//     compiler-forced vmcnt(0) drain (round-2 mistake); cross-lane LDS
//     exchange is barrier-ordered (round-3 mistake).
//   LDS 28 KB -> 5 blocks/CU.

#define OUTDIM 512
#define CTRL_N 64
#define TU 4

__global__ __launch_bounds__(256) void surf_eval_kernel(
    const float* __restrict__ ctrl,   // [B,64,64,4]
    const float* __restrict__ Nu,     // [512,4]
    const float* __restrict__ Nv,     // [512,4]
    const int*   __restrict__ iu,     // [512,4]
    const int*   __restrict__ iv,     // [512,4]
    float*       __restrict__ out)    // [B,512,512,3]
{
    __shared__ float4 rows[TU * CTRL_N];                    // 4 KB
    __shared__ __align__(16) float stg[TU][OUTDIM * 3];     // 24 KB

    const int blk = blockIdx.x;
    const int b  = blk >> 7;               // 0..63 (128 U-tiles per batch)
    const int U0 = (blk & 127) * TU;       // 0,4,...,508
    const int t  = threadIdx.x;

    // ---------- stage 1: u-contraction into LDS (1 point per thread) ----------
    {
        const int u = t >> 6;              // 0..3
        const int n = t & 63;              // 0..63
        const int U = U0 + u;
        const float4 nu  = *(const float4*)(Nu + U * 4);
        const int4   iu4 = *(const int4*)(iu + U * 4);
        const float* cb = ctrl + (size_t)b * (64 * 64 * 4);
        const float4 p0 = *(const float4*)(cb + (size_t)iu4.x * (CTRL_N * 4) + n * 4);
        const float4 p1 = *(const float4*)(cb + (size_t)iu4.y * (CTRL_N * 4) + n * 4);
        const float4 p2 = *(const float4*)(cb + (size_t)iu4.z * (CTRL_N * 4) + n * 4);
        const float4 p3 = *(const float4*)(cb + (size_t)iu4.w * (CTRL_N * 4) + n * 4);
        float4 acc;
        acc.x = nu.x * p0.x + nu.y * p1.x + nu.z * p2.x + nu.w * p3.x;
        acc.y = nu.x * p0.y + nu.y * p1.y + nu.z * p2.y + nu.w * p3.y;
        acc.z = nu.x * p0.z + nu.y * p1.z + nu.z * p2.z + nu.w * p3.z;
        acc.w = nu.x * p0.w + nu.y * p1.w + nu.z * p2.w + nu.w * p3.w;
        rows[u * CTRL_N + n] = acc;
    }
    __syncthreads();

    // ---------- stage 2: compute ALL u-rows into staging ----------
    const int v0 = t << 1;
    const float4 nvA = *(const float4*)(Nv + v0 * 4);
    const float4 nvB = *(const float4*)(Nv + v0 * 4 + 4);
    const int    iA  = iv[v0 * 4];                 // iv[2t].x
    const int    dB  = iv[v0 * 4 + 4] - iA;        // 0 or 1

    const float wB0 = dB ? 0.0f  : nvB.x;
    const float wB1 = dB ? nvB.x : nvB.y;
    const float wB2 = dB ? nvB.y : nvB.z;
    const float wB3 = dB ? nvB.z : nvB.w;
    const float wB4 = dB ? nvB.w : 0.0f;

#pragma unroll
    for (int u = 0; u < TU; ++u) {
        const float4* ru = rows + u * CTRL_N;
        const float4 q0 = ru[iA + 0];
        const float4 q1 = ru[iA + 1];
        const float4 q2 = ru[iA + 2];
        const float4 q3 = ru[iA + 3];
        const float4 q4 = ru[iA + 4];

        float sxA = nvA.x * q0.x + nvA.y * q1.x + nvA.z * q2.x + nvA.w * q3.x;
        float syA = nvA.x * q0.y + nvA.y * q1.y + nvA.z * q2.y + nvA.w * q3.y;
        float szA = nvA.x * q0.z + nvA.y * q1.z + nvA.z * q2.z + nvA.w * q3.z;
        float swA = nvA.x * q0.w + nvA.y * q1.w + nvA.z * q2.w + nvA.w * q3.w;

        float sxB = wB0 * q0.x + wB1 * q1.x + wB2 * q2.x + wB3 * q3.x + wB4 * q4.x;
        float syB = wB0 * q0.y + wB1 * q1.y + wB2 * q2.y + wB3 * q3.y + wB4 * q4.y;
        float szB = wB0 * q0.z + wB1 * q1.z + wB2 * q2.z + wB3 * q3.z + wB4 * q4.z;
        float swB = wB0 * q0.w + wB1 * q1.w + wB2 * q2.w + wB3 * q3.w + wB4 * q4.w;

        const float invA = __builtin_amdgcn_rcpf(swA);
        const float invB = __builtin_amdgcn_rcpf(swB);

        float2* sp = (float2*)&stg[u][6 * t];      // 24 B at float offset 6t
        sp[0] = make_float2(sxA * invA, syA * invA);
        sp[1] = make_float2(szA * invA, sxB * invB);
        sp[2] = make_float2(syB * invB, szB * invB);
    }
    __syncthreads();   // orders LDS staging; NO global stores pending here

    // ---------- store phase: fully coalesced, fire-and-forget ----------
    float* orow = out + ((size_t)b * OUTDIM + U0) * (OUTDIM * 3);
#pragma unroll
    for (int u = 0; u < TU; ++u) {
        const float4* sb = (const float4*)stg[u];
        float* og = orow + u * (OUTDIM * 3);       // 6144 B, 16B-aligned
        *(float4*)(og + 4 * t) = sb[t];            // chunks 0..255
        if (t < 128)
            *(float4*)(og + 4 * (256 + t)) = sb[256 + t];   // chunks 256..383
    }
}

extern "C" void kernel_launch(void* const* d_in, const int* in_sizes, int n_in,
                              void* d_out, int out_size, void* d_ws, size_t ws_size,
                              hipStream_t stream) {
    const float* ctrl = (const float*)d_in[0];
    const float* Nu   = (const float*)d_in[1];
    const float* Nv   = (const float*)d_in[2];
    const int*   iu   = (const int*)d_in[3];
    const int*   iv   = (const int*)d_in[4];
    float* out = (float*)d_out;

    // grid: 64 batches x 128 U-tiles (of 4 rows) = 8192 blocks of 256 threads
    const int nblocks = 64 * (OUTDIM / TU);
    surf_eval_kernel<<<nblocks, 256, 0, stream>>>(ctrl, Nu, Nv, iu, iv, out);
}

// Round 5
// 212.631 us; speedup vs baseline: 1.0225x; 1.0225x over previous
//
#include <hip/hip_runtime.h>

// NURBS surface eval, two-stage separable form.
//   Per block: one batch b x TU=8 U-rows. 256 threads, 4096 blocks, 8 KB LDS.
//   Stage 1: rows[u][n] = sum_l Nu[U,l]*ctrl[b,iu[U,l],n], stored SoA as two
//     float2 planes pxy/pzw (LAYOUT IS THE ROUND-5 EXPERIMENT: the AoS
//     float4 indexed ds_read_b128 gather was the suspected ~35cy/instr
//     multi-phase conflict; SoA float2 -> ds_read_b64 at idx*8, wave span
//     ~15 consecutive idx -> 30 distinct banks, no idx/idx+16 collision,
//     same-address lanes broadcast -> conflict-free by construction).
//   Stage 2: thread t owns V-pair (2t,2t+1); consecutive-base trick
//     (iv[2t+1].x - iv[2t].x in {0,1}): 5 taps cover both points, point B
//     uses a 5-wide weight vector selected once (numerics proven R2/R4).
//   Stores: direct fire-and-forget float2 (proven cost-neutral R0 vs R4);
//     no barrier after any global store.

#define OUTDIM 512
#define CTRL_N 64
#define TU 8

__global__ __launch_bounds__(256) void surf_eval_kernel(
    const float* __restrict__ ctrl,   // [B,64,64,4]
    const float* __restrict__ Nu,     // [512,4]
    const float* __restrict__ Nv,     // [512,4]
    const int*   __restrict__ iu,     // [512,4]
    const int*   __restrict__ iv,     // [512,4]
    float*       __restrict__ out)    // [B,512,512,3]
{
    __shared__ float2 pxy[TU * CTRL_N];   // 4 KB  (x,y of u-contracted rows)
    __shared__ float2 pzw[TU * CTRL_N];   // 4 KB  (z,w)

    const int blk = blockIdx.x;
    const int b  = blk >> 6;               // 0..63
    const int U0 = (blk & 63) * TU;        // 0,8,...,504
    const int t  = threadIdx.x;

    // ---------- stage 1: u-contraction into SoA LDS planes ----------
    {
        const int u  = t >> 5;             // 0..7
        const int n0 = t & 31;             // 0..31 (+32 for second point)
        const int U  = U0 + u;
        const float4 nu  = *(const float4*)(Nu + U * 4);
        const int4   iu4 = *(const int4*)(iu + U * 4);
        const float* cb = ctrl + (size_t)b * (64 * 64 * 4);
        const float* r0 = cb + (size_t)iu4.x * (CTRL_N * 4);
        const float* r1 = cb + (size_t)iu4.y * (CTRL_N * 4);
        const float* r2 = cb + (size_t)iu4.z * (CTRL_N * 4);
        const float* r3 = cb + (size_t)iu4.w * (CTRL_N * 4);

#pragma unroll
        for (int k = 0; k < 2; ++k) {
            const int n = n0 + 32 * k;
            const float4 p0 = *(const float4*)(r0 + n * 4);
            const float4 p1 = *(const float4*)(r1 + n * 4);
            const float4 p2 = *(const float4*)(r2 + n * 4);
            const float4 p3 = *(const float4*)(r3 + n * 4);
            float4 acc;
            acc.x = nu.x * p0.x + nu.y * p1.x + nu.z * p2.x + nu.w * p3.x;
            acc.y = nu.x * p0.y + nu.y * p1.y + nu.z * p2.y + nu.w * p3.y;
            acc.z = nu.x * p0.z + nu.y * p1.z + nu.z * p2.z + nu.w * p3.z;
            acc.w = nu.x * p0.w + nu.y * p1.w + nu.z * p2.w + nu.w * p3.w;
            pxy[u * CTRL_N + n] = make_float2(acc.x, acc.y);
            pzw[u * CTRL_N + n] = make_float2(acc.z, acc.w);
        }
    }
    __syncthreads();   // the only barrier; no global stores are pending here

    // ---------- stage 2: V-pair per thread, 5-tap shared gather ----------
    const int v0 = t << 1;
    const float4 nvA = *(const float4*)(Nv + v0 * 4);
    const float4 nvB = *(const float4*)(Nv + v0 * 4 + 4);
    const int    iA  = iv[v0 * 4];                 // iv[2t].x
    const int    dB  = iv[v0 * 4 + 4] - iA;        // 0 or 1

    const float wB0 = dB ? 0.0f  : nvB.x;
    const float wB1 = dB ? nvB.x : nvB.y;
    const float wB2 = dB ? nvB.y : nvB.z;
    const float wB3 = dB ? nvB.z : nvB.w;
    const float wB4 = dB ? nvB.w : 0.0f;

    const size_t obase = ((size_t)b * OUTDIM + U0) * OUTDIM;

#pragma unroll
    for (int u = 0; u < TU; ++u) {
        const float2* uxy = pxy + u * CTRL_N + iA;
        const float2* uzw = pzw + u * CTRL_N + iA;
        const float2 xy0 = uxy[0];
        const float2 xy1 = uxy[1];
        const float2 xy2 = uxy[2];
        const float2 xy3 = uxy[3];
        const float2 xy4 = uxy[4];
        const float2 zw0 = uzw[0];
        const float2 zw1 = uzw[1];
        const float2 zw2 = uzw[2];
        const float2 zw3 = uzw[3];
        const float2 zw4 = uzw[4];

        const float sxA = nvA.x * xy0.x + nvA.y * xy1.x + nvA.z * xy2.x + nvA.w * xy3.x;
        const float syA = nvA.x * xy0.y + nvA.y * xy1.y + nvA.z * xy2.y + nvA.w * xy3.y;
        const float szA = nvA.x * zw0.x + nvA.y * zw1.x + nvA.z * zw2.x + nvA.w * zw3.x;
        const float swA = nvA.x * zw0.y + nvA.y * zw1.y + nvA.z * zw2.y + nvA.w * zw3.y;

        const float sxB = wB0 * xy0.x + wB1 * xy1.x + wB2 * xy2.x + wB3 * xy3.x + wB4 * xy4.x;
        const float syB = wB0 * xy0.y + wB1 * xy1.y + wB2 * xy2.y + wB3 * xy3.y + wB4 * xy4.y;
        const float szB = wB0 * zw0.x + wB1 * zw1.x + wB2 * zw2.x + wB3 * zw3.x + wB4 * zw4.x;
        const float swB = wB0 * zw0.y + wB1 * zw1.y + wB2 * zw2.y + wB3 * zw3.y + wB4 * zw4.y;

        const float invA = __builtin_amdgcn_rcpf(swA);
        const float invB = __builtin_amdgcn_rcpf(swB);

        float* og = out + (obase + (size_t)u * OUTDIM + v0) * 3;
        *(float2*)(og + 0) = make_float2(sxA * invA, syA * invA);
        *(float2*)(og + 2) = make_float2(szA * invA, sxB * invB);
        *(float2*)(og + 4) = make_float2(syB * invB, szB * invB);
    }
}

extern "C" void kernel_launch(void* const* d_in, const int* in_sizes, int n_in,
                              void* d_out, int out_size, void* d_ws, size_t ws_size,
                              hipStream_t stream) {
    const float* ctrl = (const float*)d_in[0];
    const float* Nu   = (const float*)d_in[1];
    const float* Nv   = (const float*)d_in[2];
    const int*   iu   = (const int*)d_in[3];
    const int*   iv   = (const int*)d_in[4];
    float* out = (float*)d_out;

    // grid: 64 batches x 64 U-tiles (of 8 rows) = 4096 blocks of 256 threads
    const int nblocks = 64 * (OUTDIM / TU);
    surf_eval_kernel<<<nblocks, 256, 0, stream>>>(ctrl, Nu, Nv, iu, iv, out);
}